// Round 2
// baseline (122863.062 us; speedup 1.0000x reference)
//
#include <hip/hip_runtime.h>
#include <math.h>

#define HHW 48
#define PP  2304      // 48*48
#define MM  36864     // 16*2304

// ---------------- weight transposes ----------------
// w (Cout, Cin, 3, 3) f32 -> wt (9, Cin, Cout) f32
__global__ void tw3_k(const float* __restrict__ w, float* __restrict__ wt, int Cout, int Cin) {
    int idx = blockIdx.x * 256 + threadIdx.x;
    int n = Cout * Cin * 9;
    if (idx >= n) return;
    int co  = idx / (Cin * 9);
    int rem = idx - co * Cin * 9;
    int ci  = rem / 9;
    int kk  = rem - ci * 9;
    wt[(kk * Cin + ci) * Cout + co] = w[idx];
}

// w (O, C) f32 -> wt (C, O) f32
__global__ void tw1_k(const float* __restrict__ w, float* __restrict__ wt, int O, int Cm) {
    int idx = blockIdx.x * 256 + threadIdx.x;
    int n = O * Cm;
    if (idx >= n) return;
    int o = idx / Cm;
    int c = idx - o * Cm;
    wt[c * O + o] = w[idx];
}

// ---------------- conv3x3 (SAME), generic input layout via strides ----------------
// block 256 = 64 cout-lanes x 4 pixels; input read is wave-uniform (broadcast)
template<bool ACC>
__global__ void conv3x3_k(const float* __restrict__ in, const float* __restrict__ wt,
                          float* __restrict__ out, int CinIn, int CinT, int ciOff, int Cout,
                          long chanStride, long pixStride, long imgStride) {
    int t  = threadIdx.x;
    int co = blockIdx.y * 64 + (t & 63);
    int p  = blockIdx.x * 4 + (t >> 6);
    int b  = p / PP;
    int r  = p - b * PP;
    int y  = r / HHW;
    int x  = r - y * HHW;
    float acc = 0.f;
    const float* imgBase = in + (long)b * imgStride;
    for (int k = 0; k < 9; ++k) {
        int yy = y + k / 3 - 1;
        int xx = x + k % 3 - 1;
        if ((unsigned)yy < (unsigned)HHW && (unsigned)xx < (unsigned)HHW) {
            const float* base = imgBase + (long)(yy * HHW + xx) * pixStride;
            const float* wb   = wt + (size_t)(k * CinT + ciOff) * Cout + co;
            #pragma unroll 4
            for (int ci = 0; ci < CinIn; ++ci)
                acc += base[(long)ci * chanStride] * wb[(size_t)ci * Cout];
        }
    }
    size_t oi = (size_t)p * Cout + co;
    if (ACC) out[oi] += acc; else out[oi] = acc;
}

// ---------------- batch norm ----------------
__global__ void zero_k(float* p, int n) {
    int i = blockIdx.x * 256 + threadIdx.x;
    if (i < n) p[i] = 0.f;
}

// grid (Cout/64, 36), block 256 = 64c x 4px-lanes; 1024 px per grid.y
__global__ void bn_stats_k(const float* __restrict__ src, float* __restrict__ sum,
                           float* __restrict__ sumsq, int Cout) {
    int t  = threadIdx.x;
    int c  = blockIdx.x * 64 + (t & 63);
    int pl = t >> 6;
    int p0 = blockIdx.y * 1024;
    float s = 0.f, ss = 0.f;
    for (int i = pl; i < 1024; i += 4) {
        float v = src[(size_t)(p0 + i) * Cout + c];
        s += v; ss += v * v;
    }
    __shared__ float ls[256], lss[256];
    ls[t] = s; lss[t] = ss;
    __syncthreads();
    if (t < 64) {
        s  = ls[t]  + ls[t + 64]  + ls[t + 128]  + ls[t + 192];
        ss = lss[t] + lss[t + 64] + lss[t + 128] + lss[t + 192];
        atomicAdd(&sum[c], s);
        atomicAdd(&sumsq[c], ss);
    }
}

__global__ void bn_fin_k(const float* __restrict__ sum, const float* __restrict__ sumsq,
                         const float* __restrict__ g, const float* __restrict__ b,
                         float* __restrict__ scale, float* __restrict__ shift, int Cout) {
    int c = blockIdx.x * 256 + threadIdx.x;
    if (c >= Cout) return;
    const float invM = 1.f / 36864.f;
    float mean = sum[c] * invM;
    float var  = sumsq[c] * invM - mean * mean;
    float inv  = 1.f / sqrtf(var + 1e-5f);
    float gg = g[c], bb = b[c];
    scale[c] = gg * inv;
    shift[c] = bb - mean * gg * inv;
}

__global__ void bn_apply_k(const float* __restrict__ src, const float* __restrict__ scale,
                           const float* __restrict__ shift, float* __restrict__ dst,
                           int cmask, int n) {
    int idx = blockIdx.x * 256 + threadIdx.x;
    if (idx >= n) return;
    int c = idx & cmask;
    float y = src[idx] * scale[c] + shift[c];
    dst[idx] = fmaxf(y, 0.f);
}

// ---------------- conv1x1 (NHWC activations) ----------------
__global__ void conv1x1_k(const float* __restrict__ in, const float* __restrict__ wt,
                          const float* __restrict__ bias, float* __restrict__ out,
                          int Cc, int O) {
    int o = blockIdx.y * blockDim.x + threadIdx.x;
    int p = blockIdx.x * blockDim.y + threadIdx.y;
    const float* ib = in + (size_t)p * Cc;
    float acc = 0.f;
    #pragma unroll 4
    for (int c = 0; c < Cc; ++c) acc += ib[c] * wt[c * O + o];
    out[(size_t)p * O + o] = acc + bias[o];
}

// ---------------- criss-cross spatial attention ----------------
// block 128 per pixel; att[p][0..47]=H (diag masked), [48..95]=W; softmax over 96
__global__ void cc_logits_k(const float* __restrict__ q, const float* __restrict__ kk,
                            float* __restrict__ att) {
    int t = threadIdx.x;
    int p = blockIdx.x;
    int b = p / PP;
    int r = p - b * PP;
    int h = r / HHW;
    int w = r - h * HHW;
    __shared__ float qv[32];
    if (t < 32) qv[t] = q[p * 32 + t];
    __syncthreads();
    float val = -INFINITY;
    if (t < 48) {
        if (t != h) {
            const float* kr = kk + ((b * HHW + t) * HHW + w) * 32;
            float s = 0.f;
            #pragma unroll
            for (int c = 0; c < 32; ++c) s += qv[c] * kr[c];
            val = s;
        }
    } else if (t < 96) {
        const float* kr = kk + ((b * HHW + h) * HHW + (t - 48)) * 32;
        float s = 0.f;
        #pragma unroll
        for (int c = 0; c < 32; ++c) s += qv[c] * kr[c];
        val = s;
    }
    __shared__ float red[128];
    red[t] = val;
    __syncthreads();
    for (int st = 64; st > 0; st >>= 1) { if (t < st) red[t] = fmaxf(red[t], red[t + st]); __syncthreads(); }
    float m = red[0];
    __syncthreads();
    float e = (t < 96 && val != -INFINITY) ? expf(val - m) : 0.f;
    red[t] = e;
    __syncthreads();
    for (int st = 64; st > 0; st >>= 1) { if (t < st) red[t] += red[t + st]; __syncthreads(); }
    float inv = 1.f / red[0];
    if (t < 96) att[p * 96 + t] = e * inv;
}

// block 256 (= channel c) per pixel; in-place residual update of cc
__global__ void cc_out_k(const float* __restrict__ att, const float* __restrict__ v,
                         float* __restrict__ cc, const float* __restrict__ gptr) {
    int t = threadIdx.x;
    int p = blockIdx.x;
    __shared__ float a[96];
    if (t < 96) a[t] = att[p * 96 + t];
    __syncthreads();
    int b = p / PP;
    int r = p - b * PP;
    int h = r / HHW;
    int w = r - h * HHW;
    const float* vb = v + (size_t)b * PP * 256;
    float acc = 0.f;
    #pragma unroll 4
    for (int g = 0; g < 48; ++g)  acc += a[g]      * vb[(g * HHW + w) * 256 + t];
    #pragma unroll 4
    for (int tt = 0; tt < 48; ++tt) acc += a[48 + tt] * vb[(h * HHW + tt) * 256 + t];
    float gamma = gptr[0];
    size_t oi = (size_t)p * 256 + t;
    cc[oi] = gamma * acc + cc[oi];
}

// ---------------- batch-grid ("my") attention ----------------
// G[a][b2] = dot(q_img[a], k_img[b2]) over 32*2304 elems; 256 blocks
__global__ void gram_k(const float* __restrict__ q, const float* __restrict__ k,
                       float* __restrict__ G) {
    int t = threadIdx.x;
    int a  = blockIdx.x >> 4;
    int b2 = blockIdx.x & 15;
    const float* qa = q + a * 73728;
    const float* kb = k + b2 * 73728;
    float s = 0.f;
    for (int i = t; i < 73728; i += 256) s += qa[i] * kb[i];
    __shared__ float red[256];
    red[t] = s;
    __syncthreads();
    for (int st = 128; st > 0; st >>= 1) { if (t < st) red[t] += red[t + st]; __syncthreads(); }
    if (t == 0) G[blockIdx.x] = red[0];
}

__global__ void my_soft_k(const float* __restrict__ G, float* __restrict__ A) {
    int t = threadIdx.x;
    if (t >= 16) return;
    int i = t >> 2, j = t & 3;
    float l[8];
    for (int g = 0; g < 4; ++g) l[g] = (g == i) ? -INFINITY : G[t * 16 + g * 4 + j];
    for (int v = 0; v < 4; ++v) l[4 + v] = G[t * 16 + i * 4 + v];
    float m = l[0];
    for (int n = 1; n < 8; ++n) m = fmaxf(m, l[n]);
    float s = 0.f;
    for (int n = 0; n < 8; ++n) { l[n] = expf(l[n] - m); s += l[n]; }
    float inv = 1.f / s;
    for (int n = 0; n < 8; ++n) A[t * 8 + n] = l[n] * inv;
}

// in-place residual on my; v img stride = 2304*256 = 589824
__global__ void my_out_k(const float* __restrict__ A, const float* __restrict__ v,
                         float* __restrict__ my, const float* __restrict__ gptr) {
    int t = threadIdx.x;
    __shared__ float As[128];
    if (t < 128) As[t] = A[t];
    __syncthreads();
    int idx = blockIdx.x * 256 + t;
    int b = idx / 589824;
    int n = idx - b * 589824;
    int i = b >> 2, j = b & 3;
    float o = 0.f;
    for (int g = 0; g < 4; ++g)  o += As[b * 8 + g]      * v[(g * 4 + j) * 589824 + n];
    for (int tt = 0; tt < 4; ++tt) o += As[b * 8 + 4 + tt] * v[(i * 4 + tt) * 589824 + n];
    float gamma = gptr[0];
    my[idx] = gamma * o + my[idx];
}

// ---------------- classifier 1x1 -> f32 NCHW ----------------
__global__ void cls_k(const float* __restrict__ hsrc, const float* __restrict__ wt,
                      const float* __restrict__ bias, float* __restrict__ out) {
    int t = threadIdx.x;      // 128
    int p = blockIdx.x;
    __shared__ float hr[512];
    for (int i = t; i < 512; i += 128) hr[i] = hsrc[(size_t)p * 512 + i];
    __syncthreads();
    if (t < 21) {
        float acc = bias[t];
        #pragma unroll 4
        for (int c = 0; c < 512; ++c) acc += hr[c] * wt[c * 21 + t];
        int b = p / PP;
        int r = p - b * PP;
        out[(b * 21 + t) * PP + r] = acc;
    }
}

// ---------------- launch ----------------
extern "C" void kernel_launch(void* const* d_in, const int* in_sizes, int n_in,
                              void* d_out, int out_size, void* d_ws, size_t ws_size,
                              hipStream_t stream) {
    const float* x     = (const float*)d_in[0];
    const float* w_a   = (const float*)d_in[1];
    const float* g_a   = (const float*)d_in[2];
    const float* b_a   = (const float*)d_in[3];
    const float* ccq_w = (const float*)d_in[4];
    const float* ccq_b = (const float*)d_in[5];
    const float* cck_w = (const float*)d_in[6];
    const float* cck_b = (const float*)d_in[7];
    const float* ccv_w = (const float*)d_in[8];
    const float* ccv_b = (const float*)d_in[9];
    const float* cc_g  = (const float*)d_in[10];
    const float* w_b   = (const float*)d_in[11];
    const float* g_b   = (const float*)d_in[12];
    const float* b_b   = (const float*)d_in[13];
    const float* w_m1  = (const float*)d_in[14];
    const float* g_m1  = (const float*)d_in[15];
    const float* b_m1  = (const float*)d_in[16];
    const float* myq_w = (const float*)d_in[17];
    const float* myq_b = (const float*)d_in[18];
    const float* myk_w = (const float*)d_in[19];
    const float* myk_b = (const float*)d_in[20];
    const float* myv_w = (const float*)d_in[21];
    const float* myv_b = (const float*)d_in[22];
    const float* my_g  = (const float*)d_in[23];
    const float* w_m2  = (const float*)d_in[24];
    const float* g_m2  = (const float*)d_in[25];
    const float* b_m2  = (const float*)d_in[26];
    const float* w_c   = (const float*)d_in[27];
    const float* g_c   = (const float*)d_in[28];
    const float* b_c   = (const float*)d_in[29];
    const float* w_cls = (const float*)d_in[30];
    const float* b_cls = (const float*)d_in[31];
    float* out = (float*)d_out;

    char* ws = (char*)d_ws;
    // ---- workspace layout (fp32) ----
    size_t off = 0;
    float* cc  = (float*)(ws + off); off += (size_t)MM * 256 * 4;             // 37,748,736
    float* my  = (float*)(ws + off); off += (size_t)MM * 256 * 4;
    size_t o_t0 = off;
    float* t0  = (float*)(ws + off); off += (size_t)MM * 512 * 4;             // 75,497,472
    // q/k/v/att overlay the t0 region (never live at the same time)
    float* qb  = (float*)(ws + o_t0);
    float* kb  = (float*)(ws + o_t0 + 4718592);
    float* vb  = (float*)(ws + o_t0 + 9437184);
    float* att = (float*)(ws + o_t0 + 47185920);
    float* wat  = (float*)(ws + off); off += 9437184;
    float* wm1t = (float*)(ws + off); off += 9437184;
    float* wbt  = (float*)(ws + off); off += 2359296;
    float* wm2t = (float*)(ws + off); off += 2359296;
    float* wct  = (float*)(ws + off); off += 28311552;
    float* ccqT = (float*)(ws + off); off += 32768;
    float* cckT = (float*)(ws + off); off += 32768;
    float* ccvT = (float*)(ws + off); off += 262144;
    float* myqT = (float*)(ws + off); off += 32768;
    float* mykT = (float*)(ws + off); off += 32768;
    float* myvT = (float*)(ws + off); off += 262144;
    float* wclsT = (float*)(ws + off); off += 43008;
    float* stats = (float*)(ws + off); off += 16384;
    if (ws_size < off) return;  // insufficient workspace — fail loudly (output stays 0)
    float* ssum   = stats;
    float* ssumsq = stats + 512;
    float* sscale = stats + 1024;
    float* sshift = stats + 1536;
    float* G = stats + 2048;
    float* A = stats + 2048 + 256;

    // ---- weight transposes ----
    tw3_k<<<9216, 256, 0, stream>>>(w_a,  wat,  256, 1024);
    tw3_k<<<9216, 256, 0, stream>>>(w_m1, wm1t, 256, 1024);
    tw3_k<<<2304, 256, 0, stream>>>(w_b,  wbt,  256, 256);
    tw3_k<<<2304, 256, 0, stream>>>(w_m2, wm2t, 256, 256);
    tw3_k<<<27648, 256, 0, stream>>>(w_c, wct,  512, 1536);
    tw1_k<<<32, 256, 0, stream>>>(ccq_w, ccqT, 32, 256);
    tw1_k<<<32, 256, 0, stream>>>(cck_w, cckT, 32, 256);
    tw1_k<<<256, 256, 0, stream>>>(ccv_w, ccvT, 256, 256);
    tw1_k<<<32, 256, 0, stream>>>(myq_w, myqT, 32, 256);
    tw1_k<<<32, 256, 0, stream>>>(myk_w, mykT, 32, 256);
    tw1_k<<<256, 256, 0, stream>>>(myv_w, myvT, 256, 256);
    tw1_k<<<42, 256, 0, stream>>>(w_cls, wclsT, 21, 512);

    auto bn = [&](const float* src, const float* g, const float* b, float* dst, int Cout) {
        zero_k<<<4, 256, 0, stream>>>(ssum, 1024);
        bn_stats_k<<<dim3(Cout / 64, 36), 256, 0, stream>>>(src, ssum, ssumsq, Cout);
        bn_fin_k<<<(Cout + 255) / 256, 256, 0, stream>>>(ssum, ssumsq, g, b, sscale, sshift, Cout);
        int n = MM * Cout;
        bn_apply_k<<<n / 256, 256, 0, stream>>>(src, sscale, sshift, dst, Cout - 1, n);
    };

    const long xChan = PP, xPix = 1, xImg = (long)1024 * PP;      // x is NCHW fp32
    const long aChan = 1;                                          // activations NHWC

    // ---- branch A initial: cc = bn_relu(conv3x3(x, w_a)) ----
    conv3x3_k<false><<<dim3(9216, 4), 256, 0, stream>>>(x, wat, t0, 1024, 1024, 0, 256, xChan, xPix, xImg);
    bn(t0, g_a, b_a, cc, 256);
    // ---- branch B initial: my = bn_relu(conv3x3(x, w_m1)) ----
    conv3x3_k<false><<<dim3(9216, 4), 256, 0, stream>>>(x, wm1t, t0, 1024, 1024, 0, 256, xChan, xPix, xImg);
    bn(t0, g_m1, b_m1, my, 256);

    // ---- criss-cross spatial attention x2 (in-place on cc) ----
    for (int rec = 0; rec < 2; ++rec) {
        conv1x1_k<<<dim3(MM / 8, 1), dim3(32, 8), 0, stream>>>(cc, ccqT, ccq_b, qb, 256, 32);
        conv1x1_k<<<dim3(MM / 8, 1), dim3(32, 8), 0, stream>>>(cc, cckT, cck_b, kb, 256, 32);
        conv1x1_k<<<dim3(MM / 4, 4), dim3(64, 4), 0, stream>>>(cc, ccvT, ccv_b, vb, 256, 256);
        cc_logits_k<<<MM, 128, 0, stream>>>(qb, kb, att);
        cc_out_k<<<MM, 256, 0, stream>>>(att, vb, cc, cc_g);
    }

    // ---- batch-grid attention x2 (in-place on my) ----
    for (int rec = 0; rec < 2; ++rec) {
        conv1x1_k<<<dim3(MM / 8, 1), dim3(32, 8), 0, stream>>>(my, myqT, myq_b, qb, 256, 32);
        conv1x1_k<<<dim3(MM / 8, 1), dim3(32, 8), 0, stream>>>(my, mykT, myk_b, kb, 256, 32);
        conv1x1_k<<<dim3(MM / 4, 4), dim3(64, 4), 0, stream>>>(my, myvT, myv_b, vb, 256, 256);
        gram_k<<<256, 256, 0, stream>>>(qb, kb, G);
        my_soft_k<<<1, 64, 0, stream>>>(G, A);
        my_out_k<<<MM, 256, 0, stream>>>(A, vb, my, my_g);
    }

    // ---- post convs ----
    conv3x3_k<false><<<dim3(9216, 4), 256, 0, stream>>>(cc, wbt, t0, 256, 256, 0, 256, aChan, 256, (long)PP * 256);
    bn(t0, g_b, b_b, cc, 256);
    conv3x3_k<false><<<dim3(9216, 4), 256, 0, stream>>>(my, wm2t, t0, 256, 256, 0, 256, aChan, 256, (long)PP * 256);
    bn(t0, g_m2, b_m2, my, 256);

    // ---- concat conv (x | cc | my) -> 512 ----
    conv3x3_k<false><<<dim3(9216, 8), 256, 0, stream>>>(x,  wct, t0, 1024, 1536, 0,    512, xChan, xPix, xImg);
    conv3x3_k<true><<<dim3(9216, 8), 256, 0, stream>>>(cc, wct, t0, 256,  1536, 1024, 512, aChan, 256, (long)PP * 256);
    conv3x3_k<true><<<dim3(9216, 8), 256, 0, stream>>>(my, wct, t0, 256,  1536, 1280, 512, aChan, 256, (long)PP * 256);
    bn(t0, g_c, b_c, t0, 512);

    // ---- classifier ----
    cls_k<<<MM, 128, 0, stream>>>(t0, wclsT, b_cls, out);
}

// Round 3
// 3909.175 us; speedup vs baseline: 31.4294x; 31.4294x over previous
//
#include <hip/hip_runtime.h>
#include <hip/hip_bf16.h>
#include <math.h>

typedef __hip_bfloat16 bf16;
typedef unsigned short ushort;
typedef __attribute__((ext_vector_type(8))) short bh8;
typedef __attribute__((ext_vector_type(4))) float f4;

#define HHW 48
#define PP  2304      // 48*48
#define MM  36864     // 16*2304

__device__ __forceinline__ float ldf(const float* p) { return *p; }
__device__ __forceinline__ float ldf(const bf16* p) { return __bfloat162float(*p); }
__device__ __forceinline__ void stf(float* p, float v) { *p = v; }
__device__ __forceinline__ void stf(bf16* p, float v) { *p = __float2bfloat16(v); }

// ---------------- prep kernels ----------------
// x (16,1024,48,48) f32 NCHW -> xb (36864, 1024) bf16 NHWC, 32x32 LDS tile transpose
__global__ void x2b_k(const float* __restrict__ x, bf16* __restrict__ xb) {
    __shared__ float tile[32][33];
    int b  = blockIdx.z;
    int c0 = blockIdx.y * 32;
    int p0 = blockIdx.x * 32;
    int lp = threadIdx.x & 31;
    int cg = threadIdx.x >> 5;   // 0..7
    #pragma unroll
    for (int j = 0; j < 4; ++j) {
        int c = cg * 4 + j;
        tile[c][lp] = x[((size_t)b * 1024 + c0 + c) * PP + p0 + lp];
    }
    __syncthreads();
    #pragma unroll
    for (int j = 0; j < 4; ++j) {
        int rp = cg * 4 + j;
        xb[((size_t)b * PP + p0 + rp) * 1024 + c0 + lp] = __float2bfloat16(tile[lp][rp]);
    }
}

// w (Cout, Cin, 3, 3) f32 -> wb (9, Cout, Cin) bf16
__global__ void w3b_k(const float* __restrict__ w, bf16* __restrict__ wb, int Cout, int Cin) {
    int idx = blockIdx.x * 256 + threadIdx.x;
    int n = Cout * Cin * 9;
    if (idx >= n) return;
    int kk  = idx / (Cout * Cin);
    int rem = idx - kk * Cout * Cin;
    int co  = rem / Cin;
    int ci  = rem - co * Cin;
    wb[idx] = __float2bfloat16(w[((size_t)co * Cin + ci) * 9 + kk]);
}

// flat f32 -> bf16
__global__ void f2b_k(const float* __restrict__ s, bf16* __restrict__ d, int n) {
    int i = blockIdx.x * 256 + threadIdx.x;
    if (i < n) d[i] = __float2bfloat16(s[i]);
}

// w (O, C) f32 -> wt (C, O) f32  (for q/k/cls small GEMVs)
__global__ void tw1_k(const float* __restrict__ w, float* __restrict__ wt, int O, int Cm) {
    int idx = blockIdx.x * 256 + threadIdx.x;
    int n = O * Cm;
    if (idx >= n) return;
    int o = idx / Cm;
    int c = idx - o * Cm;
    wt[c * O + o] = w[idx];
}

// ---------------- MFMA implicit-GEMM conv ----------------
// in: [36864, Cin] bf16 NHWC.  wt: [kcnt, Cout, CinT] bf16 (ci contiguous).
// out: [36864, Cout] OutT.  SAME 3x3 when kcnt==9 (dy,dx from k9), 1x1 when kcnt==1.
// block 256 = 4 waves; tile 128 px x 128 co; wave tile 64x64 (4x4 of 16x16x32).
template<typename OutT>
__global__ __launch_bounds__(256, 2)
void mconv_k(const bf16* __restrict__ in, const bf16* __restrict__ wt,
             const float* __restrict__ bias, OutT* __restrict__ out,
             int Cin, int CinT, int ciOff, int Cout, int kcnt, int accum) {
    __shared__ ushort As[128 * 40];   // stride 40 (80B): <=2-way bank aliasing, 16B aligned
    __shared__ ushort Bs[128 * 40];
    const ushort* inu = (const ushort*)in;
    const ushort* wtu = (const ushort*)wt;
    int tid = threadIdx.x;
    int N0 = blockIdx.x * 128;
    int M0 = blockIdx.y * 128;
    // staging: thread -> rows (sr, sr+64), 8-ci column group sc
    int sr = tid >> 2;
    int sc = (tid & 3) * 8;
    int p0 = M0 + sr, p1 = p0 + 64;
    int rr0 = p0 % PP, rr1 = p1 % PP;
    int y0 = rr0 / HHW, x0 = rr0 - y0 * HHW;
    int y1 = rr1 / HHW, x1 = rr1 - y1 * HHW;
    // wave tiling
    int wv = tid >> 6, lane = tid & 63;
    int wm = (wv & 1) * 64, wn = (wv >> 1) * 64;
    int l15 = lane & 15, quad = lane >> 4;

    f4 acc[4][4];
    #pragma unroll
    for (int i = 0; i < 4; ++i)
        #pragma unroll
        for (int j = 0; j < 4; ++j) acc[i][j] = (f4){0.f, 0.f, 0.f, 0.f};

    uint4 z4; z4.x = z4.y = z4.z = z4.w = 0;

    for (int k9 = 0; k9 < kcnt; ++k9) {
        int dy = (kcnt == 1) ? 0 : (k9 / 3 - 1);
        int dx = (kcnt == 1) ? 0 : (k9 % 3 - 1);
        bool v0 = ((unsigned)(y0 + dy) < (unsigned)HHW) && ((unsigned)(x0 + dx) < (unsigned)HHW);
        bool v1 = ((unsigned)(y1 + dy) < (unsigned)HHW) && ((unsigned)(x1 + dx) < (unsigned)HHW);
        const ushort* a0p = inu + (size_t)(p0 + dy * HHW + dx) * Cin + sc;
        const ushort* a1p = inu + (size_t)(p1 + dy * HHW + dx) * Cin + sc;
        const ushort* w0p = wtu + ((size_t)k9 * Cout + N0 + sr) * CinT + ciOff + sc;
        const ushort* w1p = w0p + (size_t)64 * CinT;
        for (int c0 = 0; c0 < Cin; c0 += 32) {
            __syncthreads();
            const uint4* pa0 = (const uint4*)(v0 ? (a0p + c0) : inu);
            const uint4* pa1 = (const uint4*)(v1 ? (a1p + c0) : inu);
            uint4 av0 = *pa0; if (!v0) av0 = z4;
            uint4 av1 = *pa1; if (!v1) av1 = z4;
            uint4 bv0 = *(const uint4*)(w0p + c0);
            uint4 bv1 = *(const uint4*)(w1p + c0);
            *(uint4*)(As + sr * 40 + sc) = av0;
            *(uint4*)(As + (sr + 64) * 40 + sc) = av1;
            *(uint4*)(Bs + sr * 40 + sc) = bv0;
            *(uint4*)(Bs + (sr + 64) * 40 + sc) = bv1;
            __syncthreads();
            bh8 af[4], bfr[4];
            #pragma unroll
            for (int mi = 0; mi < 4; ++mi)
                af[mi] = *(const bh8*)(As + (wm + mi * 16 + l15) * 40 + quad * 8);
            #pragma unroll
            for (int ni = 0; ni < 4; ++ni)
                bfr[ni] = *(const bh8*)(Bs + (wn + ni * 16 + l15) * 40 + quad * 8);
            #pragma unroll
            for (int mi = 0; mi < 4; ++mi)
                #pragma unroll
                for (int ni = 0; ni < 4; ++ni)
                    acc[mi][ni] = __builtin_amdgcn_mfma_f32_16x16x32_bf16(af[mi], bfr[ni], acc[mi][ni], 0, 0, 0);
        }
    }

    // epilogue: C/D layout col=lane&15, row=quad*4+reg  [m89-verified]
    float bvn[4];
    #pragma unroll
    for (int ni = 0; ni < 4; ++ni)
        bvn[ni] = bias ? bias[N0 + wn + ni * 16 + l15] : 0.f;
    #pragma unroll
    for (int mi = 0; mi < 4; ++mi) {
        int mrow = M0 + wm + mi * 16 + quad * 4;
        #pragma unroll
        for (int ni = 0; ni < 4; ++ni) {
            int ncol = N0 + wn + ni * 16 + l15;
            #pragma unroll
            for (int r = 0; r < 4; ++r) {
                size_t oi = (size_t)(mrow + r) * Cout + ncol;
                float val = acc[mi][ni][r] + bvn[ni];
                if (accum) stf(&out[oi], ldf(&out[oi]) + val);
                else       stf(&out[oi], val);
            }
        }
    }
}

// ---------------- batch norm ----------------
__global__ void zero_k(float* p, int n) {
    int i = blockIdx.x * 256 + threadIdx.x;
    if (i < n) p[i] = 0.f;
}

template<typename S>
__global__ void bn_stats_k(const S* __restrict__ src, float* __restrict__ sum,
                           float* __restrict__ sumsq, int Cout) {
    int t  = threadIdx.x;
    int c  = blockIdx.x * 64 + (t & 63);
    int pl = t >> 6;
    int p0 = blockIdx.y * 1024;
    float s = 0.f, ss = 0.f;
    for (int i = pl; i < 1024; i += 4) {
        float v = ldf(&src[(size_t)(p0 + i) * Cout + c]);
        s += v; ss += v * v;
    }
    __shared__ float ls[256], lss[256];
    ls[t] = s; lss[t] = ss;
    __syncthreads();
    if (t < 64) {
        s  = ls[t]  + ls[t + 64]  + ls[t + 128]  + ls[t + 192];
        ss = lss[t] + lss[t + 64] + lss[t + 128] + lss[t + 192];
        atomicAdd(&sum[c], s);
        atomicAdd(&sumsq[c], ss);
    }
}

__global__ void bn_fin_k(const float* __restrict__ sum, const float* __restrict__ sumsq,
                         const float* __restrict__ g, const float* __restrict__ b,
                         float* __restrict__ scale, float* __restrict__ shift, int Cout) {
    int c = blockIdx.x * 256 + threadIdx.x;
    if (c >= Cout) return;
    const float invM = 1.f / 36864.f;
    float mean = sum[c] * invM;
    float var  = sumsq[c] * invM - mean * mean;
    float inv  = 1.f / sqrtf(var + 1e-5f);
    scale[c] = g[c] * inv;
    shift[c] = b[c] - mean * g[c] * inv;
}

template<typename S, typename D>
__global__ void bn_apply_k(const S* __restrict__ src, const float* __restrict__ scale,
                           const float* __restrict__ shift, D* __restrict__ dst,
                           int cmask, int n) {
    int idx = blockIdx.x * 256 + threadIdx.x;
    if (idx >= n) return;
    int c = idx & cmask;
    float y = ldf(&src[idx]) * scale[c] + shift[c];
    stf(&dst[idx], fmaxf(y, 0.f));
}

// ---------------- conv1x1 q/k (bf16 in, f32 wt (C,O), f32 out) ----------------
__global__ void conv1x1_k(const bf16* __restrict__ in, const float* __restrict__ wt,
                          const float* __restrict__ bias, float* __restrict__ out,
                          int Cc, int O) {
    int o = threadIdx.x;                       // 32
    int p = blockIdx.x * blockDim.y + threadIdx.y;
    const bf16* ib = in + (size_t)p * Cc;
    float acc = 0.f;
    #pragma unroll 4
    for (int c = 0; c < Cc; ++c) acc += __bfloat162float(ib[c]) * wt[c * O + o];
    out[(size_t)p * O + o] = acc + bias[o];
}

// ---------------- criss-cross spatial attention ----------------
__global__ void cc_logits_k(const float* __restrict__ q, const float* __restrict__ kk,
                            float* __restrict__ att) {
    int t = threadIdx.x;
    int p = blockIdx.x;
    int b = p / PP;
    int r = p - b * PP;
    int h = r / HHW;
    int w = r - h * HHW;
    __shared__ float qv[32];
    if (t < 32) qv[t] = q[p * 32 + t];
    __syncthreads();
    float val = -INFINITY;
    if (t < 48) {
        if (t != h) {
            const float* kr = kk + ((b * HHW + t) * HHW + w) * 32;
            float s = 0.f;
            #pragma unroll
            for (int c = 0; c < 32; ++c) s += qv[c] * kr[c];
            val = s;
        }
    } else if (t < 96) {
        const float* kr = kk + ((b * HHW + h) * HHW + (t - 48)) * 32;
        float s = 0.f;
        #pragma unroll
        for (int c = 0; c < 32; ++c) s += qv[c] * kr[c];
        val = s;
    }
    __shared__ float red[128];
    red[t] = val;
    __syncthreads();
    for (int st = 64; st > 0; st >>= 1) { if (t < st) red[t] = fmaxf(red[t], red[t + st]); __syncthreads(); }
    float m = red[0];
    __syncthreads();
    float e = (t < 96 && val != -INFINITY) ? expf(val - m) : 0.f;
    red[t] = e;
    __syncthreads();
    for (int st = 64; st > 0; st >>= 1) { if (t < st) red[t] += red[t + st]; __syncthreads(); }
    float inv = 1.f / red[0];
    if (t < 96) att[p * 96 + t] = e * inv;
}

// block 256 (= channel) per pixel; in-place bf16 residual update of cc
__global__ void cc_out_k(const float* __restrict__ att, const float* __restrict__ v,
                         bf16* __restrict__ cc, const float* __restrict__ gptr) {
    int t = threadIdx.x;
    int p = blockIdx.x;
    __shared__ float a[96];
    if (t < 96) a[t] = att[p * 96 + t];
    __syncthreads();
    int b = p / PP;
    int r = p - b * PP;
    int h = r / HHW;
    int w = r - h * HHW;
    const float* vb = v + (size_t)b * PP * 256;
    float acc = 0.f;
    #pragma unroll 4
    for (int g = 0; g < 48; ++g)   acc += a[g]      * vb[(g * HHW + w) * 256 + t];
    #pragma unroll 4
    for (int tt = 0; tt < 48; ++tt) acc += a[48 + tt] * vb[(h * HHW + tt) * 256 + t];
    float gamma = gptr[0];
    size_t oi = (size_t)p * 256 + t;
    cc[oi] = __float2bfloat16(gamma * acc + __bfloat162float(cc[oi]));
}

// ---------------- batch-grid ("my") attention ----------------
__global__ void gram_k(const float* __restrict__ q, const float* __restrict__ k,
                       float* __restrict__ G) {
    int t = threadIdx.x;
    int a  = blockIdx.x >> 4;
    int b2 = blockIdx.x & 15;
    const float* qa = q + a * 73728;
    const float* kb = k + b2 * 73728;
    float s = 0.f;
    for (int i = t; i < 73728; i += 256) s += qa[i] * kb[i];
    __shared__ float red[256];
    red[t] = s;
    __syncthreads();
    for (int st = 128; st > 0; st >>= 1) { if (t < st) red[t] += red[t + st]; __syncthreads(); }
    if (t == 0) G[blockIdx.x] = red[0];
}

__global__ void my_soft_k(const float* __restrict__ G, float* __restrict__ A) {
    int t = threadIdx.x;
    if (t >= 16) return;
    int i = t >> 2, j = t & 3;
    float l[8];
    for (int g = 0; g < 4; ++g) l[g] = (g == i) ? -INFINITY : G[t * 16 + g * 4 + j];
    for (int v = 0; v < 4; ++v) l[4 + v] = G[t * 16 + i * 4 + v];
    float m = l[0];
    for (int n = 1; n < 8; ++n) m = fmaxf(m, l[n]);
    float s = 0.f;
    for (int n = 0; n < 8; ++n) { l[n] = expf(l[n] - m); s += l[n]; }
    float inv = 1.f / s;
    for (int n = 0; n < 8; ++n) A[t * 8 + n] = l[n] * inv;
}

__global__ void my_out_k(const float* __restrict__ A, const float* __restrict__ v,
                         bf16* __restrict__ my, const float* __restrict__ gptr) {
    int t = threadIdx.x;
    __shared__ float As[128];
    if (t < 128) As[t] = A[t];
    __syncthreads();
    int idx = blockIdx.x * 256 + t;
    int b = idx / 589824;
    int n = idx - b * 589824;
    int i = b >> 2, j = b & 3;
    float o = 0.f;
    for (int g = 0; g < 4; ++g)   o += As[b * 8 + g]      * v[(g * 4 + j) * 589824 + n];
    for (int tt = 0; tt < 4; ++tt) o += As[b * 8 + 4 + tt] * v[(i * 4 + tt) * 589824 + n];
    float gamma = gptr[0];
    my[idx] = __float2bfloat16(gamma * o + __bfloat162float(my[idx]));
}

// ---------------- classifier 1x1 -> f32 NCHW ----------------
__global__ void cls_k(const float* __restrict__ hsrc, const float* __restrict__ wt,
                      const float* __restrict__ bias, float* __restrict__ out) {
    int t = threadIdx.x;      // 128
    int p = blockIdx.x;
    __shared__ float hr[512];
    for (int i = t; i < 512; i += 128) hr[i] = hsrc[(size_t)p * 512 + i];
    __syncthreads();
    if (t < 21) {
        float acc = bias[t];
        #pragma unroll 4
        for (int c = 0; c < 512; ++c) acc += hr[c] * wt[c * 21 + t];
        int b = p / PP;
        int r = p - b * PP;
        out[(b * 21 + t) * PP + r] = acc;
    }
}

// ---------------- launch ----------------
extern "C" void kernel_launch(void* const* d_in, const int* in_sizes, int n_in,
                              void* d_out, int out_size, void* d_ws, size_t ws_size,
                              hipStream_t stream) {
    const float* x     = (const float*)d_in[0];
    const float* w_a   = (const float*)d_in[1];
    const float* g_a   = (const float*)d_in[2];
    const float* b_a   = (const float*)d_in[3];
    const float* ccq_w = (const float*)d_in[4];
    const float* ccq_b = (const float*)d_in[5];
    const float* cck_w = (const float*)d_in[6];
    const float* cck_b = (const float*)d_in[7];
    const float* ccv_w = (const float*)d_in[8];
    const float* ccv_b = (const float*)d_in[9];
    const float* cc_g  = (const float*)d_in[10];
    const float* w_b   = (const float*)d_in[11];
    const float* g_b   = (const float*)d_in[12];
    const float* b_b   = (const float*)d_in[13];
    const float* w_m1  = (const float*)d_in[14];
    const float* g_m1  = (const float*)d_in[15];
    const float* b_m1  = (const float*)d_in[16];
    const float* myq_w = (const float*)d_in[17];
    const float* myq_b = (const float*)d_in[18];
    const float* myk_w = (const float*)d_in[19];
    const float* myk_b = (const float*)d_in[20];
    const float* myv_w = (const float*)d_in[21];
    const float* myv_b = (const float*)d_in[22];
    const float* my_g  = (const float*)d_in[23];
    const float* w_m2  = (const float*)d_in[24];
    const float* g_m2  = (const float*)d_in[25];
    const float* b_m2  = (const float*)d_in[26];
    const float* w_c   = (const float*)d_in[27];
    const float* g_c   = (const float*)d_in[28];
    const float* b_c   = (const float*)d_in[29];
    const float* w_cls = (const float*)d_in[30];
    const float* b_cls = (const float*)d_in[31];
    float* out = (float*)d_out;

    char* ws = (char*)d_ws;
    size_t off = 0;
    bf16* cc  = (bf16*)(ws + off); off += (size_t)MM * 256 * 2;     // 18,874,368
    bf16* my  = (bf16*)(ws + off); off += (size_t)MM * 256 * 2;
    char* hx  = ws + off;          off += (size_t)MM * 256 * 4;     // 37,748,736 (f32 256 OR bf16 512)
    char* B   = ws + off;          off += (size_t)MM * 512 * 4;     // 75,497,472 multi-use
    bf16* wab  = (bf16*)(ws + off); off += 4718592;
    bf16* wm1b = (bf16*)(ws + off); off += 4718592;
    bf16* wbb  = (bf16*)(ws + off); off += 1179648;
    bf16* wm2b = (bf16*)(ws + off); off += 1179648;
    bf16* wcb  = (bf16*)(ws + off); off += 14155776;
    bf16* wvcb = (bf16*)(ws + off); off += 131072;
    bf16* wvmb = (bf16*)(ws + off); off += 131072;
    float* ccqT = (float*)(ws + off); off += 32768;
    float* cckT = (float*)(ws + off); off += 32768;
    float* myqT = (float*)(ws + off); off += 32768;
    float* mykT = (float*)(ws + off); off += 32768;
    float* wclsT = (float*)(ws + off); off += 43008;
    float* stats = (float*)(ws + off); off += 16384;
    if (ws_size < off) return;   // ~177.4 MB
    float* ssum   = stats;
    float* ssumsq = stats + 512;
    float* sscale = stats + 1024;
    float* sshift = stats + 1536;
    float* G = stats + 2048;
    float* A = stats + 2048 + 256;

    // region B sub-views
    bf16*  xbf = (bf16*)B;                           // [36864,1024] early
    float* qb  = (float*)B;                          // attention phase
    float* kb  = (float*)(B + 4718592);
    float* vb  = (float*)(B + 9437184);              // [36864,256] f32
    float* att = (float*)(B + 47185920);             // [36864,96]  f32
    float* hxf = (float*)hx;                         // conv scratch f32 [36864,256]
    bf16*  hxb = (bf16*)hx;                          // concat accum bf16 [36864,512]
    float* hfin = (float*)B;                         // final BN output f32 [36864,512]

    // ---- prep ----
    x2b_k<<<dim3(72, 32, 16), 256, 0, stream>>>(x, xbf);
    w3b_k<<<9216, 256, 0, stream>>>(w_a,  wab,  256, 1024);
    w3b_k<<<9216, 256, 0, stream>>>(w_m1, wm1b, 256, 1024);
    w3b_k<<<2304, 256, 0, stream>>>(w_b,  wbb,  256, 256);
    w3b_k<<<2304, 256, 0, stream>>>(w_m2, wm2b, 256, 256);
    w3b_k<<<27648, 256, 0, stream>>>(w_c, wcb,  512, 1536);
    f2b_k<<<256, 256, 0, stream>>>(ccv_w, wvcb, 65536);
    f2b_k<<<256, 256, 0, stream>>>(myv_w, wvmb, 65536);
    tw1_k<<<32, 256, 0, stream>>>(ccq_w, ccqT, 32, 256);
    tw1_k<<<32, 256, 0, stream>>>(cck_w, cckT, 32, 256);
    tw1_k<<<32, 256, 0, stream>>>(myq_w, myqT, 32, 256);
    tw1_k<<<32, 256, 0, stream>>>(myk_w, mykT, 32, 256);
    tw1_k<<<42, 256, 0, stream>>>(w_cls, wclsT, 21, 512);

    auto bn = [&](auto* src, const float* g, const float* b, auto* dst, int Cout) {
        zero_k<<<4, 256, 0, stream>>>(ssum, 1024);
        bn_stats_k<<<dim3(Cout / 64, 36), 256, 0, stream>>>(src, ssum, ssumsq, Cout);
        bn_fin_k<<<(Cout + 255) / 256, 256, 0, stream>>>(ssum, ssumsq, g, b, sscale, sshift, Cout);
        int n = MM * Cout;
        bn_apply_k<<<n / 256, 256, 0, stream>>>(src, sscale, sshift, dst, Cout - 1, n);
    };

    // ---- initial convs (read xbf in B) ----
    mconv_k<float><<<dim3(2, 288), 256, 0, stream>>>(xbf, wab, nullptr, hxf, 1024, 1024, 0, 256, 9, 0);
    bn(hxf, g_a, b_a, cc, 256);
    mconv_k<float><<<dim3(2, 288), 256, 0, stream>>>(xbf, wm1b, nullptr, hxf, 1024, 1024, 0, 256, 9, 0);
    bn(hxf, g_m1, b_m1, my, 256);
    // concat x-part now (before B is reused): -> hx as bf16 [36864,512]
    mconv_k<bf16><<<dim3(4, 288), 256, 0, stream>>>(xbf, wcb, nullptr, hxb, 1024, 1536, 0, 512, 9, 0);

    // ---- criss-cross spatial attention x2 (bf16 cc in-place) ----
    for (int rec = 0; rec < 2; ++rec) {
        conv1x1_k<<<dim3(MM / 8), dim3(32, 8), 0, stream>>>(cc, ccqT, ccq_b, qb, 256, 32);
        conv1x1_k<<<dim3(MM / 8), dim3(32, 8), 0, stream>>>(cc, cckT, cck_b, kb, 256, 32);
        mconv_k<float><<<dim3(2, 288), 256, 0, stream>>>(cc, wvcb, ccv_b, vb, 256, 256, 0, 256, 1, 0);
        cc_logits_k<<<MM, 128, 0, stream>>>(qb, kb, att);
        cc_out_k<<<MM, 256, 0, stream>>>(att, vb, cc, cc_g);
    }

    // ---- batch-grid attention x2 (bf16 my in-place) ----
    for (int rec = 0; rec < 2; ++rec) {
        conv1x1_k<<<dim3(MM / 8), dim3(32, 8), 0, stream>>>(my, myqT, myq_b, qb, 256, 32);
        conv1x1_k<<<dim3(MM / 8), dim3(32, 8), 0, stream>>>(my, mykT, myk_b, kb, 256, 32);
        mconv_k<float><<<dim3(2, 288), 256, 0, stream>>>(my, wvmb, myv_b, vb, 256, 256, 0, 256, 1, 0);
        gram_k<<<256, 256, 0, stream>>>(qb, kb, G);
        my_soft_k<<<1, 64, 0, stream>>>(G, A);
        my_out_k<<<MM, 256, 0, stream>>>(A, vb, my, my_g);
    }

    // ---- post convs (outputs -> B as f32 scratch; B attention data dead) ----
    float* pscr = (float*)B;
    mconv_k<float><<<dim3(2, 288), 256, 0, stream>>>(cc, wbb, nullptr, pscr, 256, 256, 0, 256, 9, 0);
    bn(pscr, g_b, b_b, cc, 256);
    mconv_k<float><<<dim3(2, 288), 256, 0, stream>>>(my, wm2b, nullptr, pscr, 256, 256, 0, 256, 9, 0);
    bn(pscr, g_m2, b_m2, my, 256);

    // ---- concat cc/my parts accumulate into hxb ----
    mconv_k<bf16><<<dim3(4, 288), 256, 0, stream>>>(cc, wcb, nullptr, hxb, 256, 1536, 1024, 512, 9, 1);
    mconv_k<bf16><<<dim3(4, 288), 256, 0, stream>>>(my, wcb, nullptr, hxb, 256, 1536, 1280, 512, 9, 1);
    bn(hxb, g_c, b_c, hfin, 512);

    // ---- classifier ----
    cls_k<<<MM, 128, 0, stream>>>(hfin, wclsT, b_cls, out);
}